// Round 8
// baseline (373.294 us; speedup 1.0000x reference)
//
#include <hip/hip_runtime.h>
#include <math.h>

#define EPS 1.55e-05f
#define PIX 36864   // 4*96*96
#define IMG 9216    // 96*96

typedef __attribute__((ext_vector_type(8))) short short8v;
typedef __attribute__((ext_vector_type(4))) short short4v;
typedef __attribute__((ext_vector_type(4))) float float4v;
typedef __attribute__((ext_vector_type(4))) unsigned short ushort4v;
typedef __attribute__((ext_vector_type(2))) unsigned int uint2v;

static __device__ __forceinline__ unsigned short f2bf(float f) {
    unsigned u = __float_as_uint(f);
    unsigned r = (u + 0x7FFFu + ((u >> 16) & 1u)) >> 16;
    return (unsigned short)r;
}
static __device__ __forceinline__ float bflo(unsigned d) {   // even channel (low 16)
    return __uint_as_float(d << 16);
}
static __device__ __forceinline__ float bfhi(unsigned d) {   // odd channel (high 16)
    return __uint_as_float(d & 0xffff0000u);
}

// ---------------- relative position bias (6 heads x 9 taps) ----------------
__global__ __launch_bounds__(512)
void relbias_kernel(const float* __restrict__ w1, const float* __restrict__ b1,
                    const float* __restrict__ w2, float* __restrict__ rb)
{
    __shared__ float hid[9][512];
    int i = threadIdx.x;
    const float s0 = -0.7739760316291208f, s2 = 0.7739760316291208f;
    float sv[3]; sv[0] = s0; sv[1] = 0.f; sv[2] = s2;
    float w1a = w1[i], w1b = w1[512 + i], bb = b1[i];
    #pragma unroll
    for (int j = 0; j < 9; j++) {
        float t0 = sv[j / 3], t1 = sv[j % 3];
        hid[j][i] = fmaxf(t0 * w1a + t1 * w1b + bb, 0.f);
    }
    __syncthreads();
    if (i < 54) {
        int he = i / 9, t = i % 9, j = 8 - t;
        float acc = 0.f;
        for (int u = 0; u < 512; u++) acc += hid[j][u] * w2[u * 6 + he];
        rb[he * 9 + t] = 16.f / (1.f + expf(-acc));
    }
}

// ---------------- prep: x->bf16, qkv_w^T->bf16, proj_w^T->bf16 ----------------
__global__ __launch_bounds__(256)
void prep_kernel(const float* __restrict__ x, const float* __restrict__ qkv_w,
                 const float* __restrict__ proj_w,
                 unsigned short* __restrict__ xs, unsigned short* __restrict__ Bt,
                 unsigned short* __restrict__ Bt2)
{
    int tid = blockIdx.x * 256 + threadIdx.x;
    int stride = gridDim.x * 256;
    int total_x4 = PIX * 192 / 4;
    for (int i = tid; i < total_x4; i += stride) {
        float4 v = ((const float4*)x)[i];
        ushort4v o;
        o.x = f2bf(v.x); o.y = f2bf(v.y); o.z = f2bf(v.z); o.w = f2bf(v.w);
        ((ushort4v*)xs)[i] = o;
    }
    for (int i = tid; i < 576 * 192; i += stride) {
        int n = i / 192, k = i - n * 192;
        Bt[i] = f2bf(qkv_w[k * 576 + n]);
    }
    for (int i = tid; i < 192 * 192; i += stride) {
        int n = i / 192, k = i - n * 192;
        Bt2[i] = f2bf(proj_w[k * 192 + n]);
    }
}

// ---------------- MFMA bf16 GEMM: C = A(MxK=192) * Bt^T + bias ----------------
// A: [M][192] bf16 row-major. Bt: [N][192] bf16 (n-major, k contiguous).
// MODE 0: store C as 8-channel-interleaved planes qkv8[n/8][PIX][8] bf16 + qkv bias.
// MODE 1: store fp32 [m][192] + bias.
template<int MODE>
__global__ __launch_bounds__(256)
void mfma_gemm_kernel(const unsigned short* __restrict__ Abf,
                      const unsigned short* __restrict__ Btb,
                      void* __restrict__ Cout,
                      const float* __restrict__ bias0,
                      const float* __restrict__ bias1)
{
    const int K = 192;
    __shared__ short smem[128 * 64 + 64 * 64];   // As | Bs ; reused as epilogue buffer
    short* As = smem;
    short* Bs = smem + 128 * 64;
    int tid = threadIdx.x;
    int m0 = blockIdx.y * 128;
    int n0 = blockIdx.x * 64;
    int lane = tid & 63, wid = tid >> 6;
    int wm = wid >> 1, wn = wid & 1;
    int lr = lane & 15, lk = lane >> 4;

    float4v acc[4][2];
    #pragma unroll
    for (int a = 0; a < 4; a++)
        #pragma unroll
        for (int b = 0; b < 2; b++)
            #pragma unroll
            for (int e = 0; e < 4; e++) acc[a][b][e] = 0.f;

    int sr = tid >> 3;          // 0..31
    int sc = tid & 7;           // 0..7 (16B chunk)
    for (int k0 = 0; k0 < K; k0 += 64) {
        #pragma unroll
        for (int i = 0; i < 4; i++) {
            int r = sr + i * 32;
            short8v v = *(const short8v*)(Abf + (size_t)(m0 + r) * K + k0 + sc * 8);
            *(short8v*)(As + r * 64 + ((sc ^ (r & 7)) * 8)) = v;
        }
        #pragma unroll
        for (int i = 0; i < 2; i++) {
            int r = sr + i * 32;
            short8v v = *(const short8v*)(Btb + (size_t)(n0 + r) * K + k0 + sc * 8);
            *(short8v*)(Bs + r * 64 + ((sc ^ (r & 7)) * 8)) = v;
        }
        __syncthreads();
        #pragma unroll
        for (int ks = 0; ks < 2; ks++) {
            short8v af[4], bf[2];
            #pragma unroll
            for (int fm = 0; fm < 4; fm++) {
                int r = wm * 64 + fm * 16 + lr;
                int c = (ks * 4 + lk) ^ (r & 7);
                af[fm] = *(const short8v*)(As + r * 64 + c * 8);
            }
            #pragma unroll
            for (int fn = 0; fn < 2; fn++) {
                int r = wn * 32 + fn * 16 + lr;
                int c = (ks * 4 + lk) ^ (r & 7);
                bf[fn] = *(const short8v*)(Bs + r * 64 + c * 8);
            }
            #pragma unroll
            for (int fm = 0; fm < 4; fm++)
                #pragma unroll
                for (int fn = 0; fn < 2; fn++)
                    acc[fm][fn] = __builtin_amdgcn_mfma_f32_16x16x32_bf16(
                        af[fm], bf[fn], acc[fm][fn], 0, 0, 0);
        }
        __syncthreads();
    }

    if (MODE == 0) {
        // stage C tile bf16 into LDS as T[m 0..127][n 0..63], row pad 74
        const int TP = 74;
        unsigned short* T = (unsigned short*)smem;
        #pragma unroll
        for (int fm = 0; fm < 4; fm++) {
            #pragma unroll
            for (int fn = 0; fn < 2; fn++) {
                int n = wn * 32 + fn * 16 + lr;
                int gn = n0 + n;
                float bv = (gn < 192) ? bias0[gn] : ((gn < 384) ? 0.f : bias1[gn - 384]);
                #pragma unroll
                for (int e = 0; e < 4; e++) {
                    int m = wm * 64 + fm * 16 + lk * 4 + e;
                    T[m * TP + n] = f2bf(acc[fm][fn][e] + bv);
                }
            }
        }
        __syncthreads();
        unsigned short* qkv8 = (unsigned short*)Cout;
        #pragma unroll
        for (int i = 0; i < 4; i++) {
            int u = tid + 256 * i;            // 0..1023
            int m = u & 127, cgl = u >> 7;    // 8 local channel-groups
            short8v vv = *(const short8v*)(T + m * TP + cgl * 8);
            int gcg = (n0 >> 3) + cgl;
            *(short8v*)(qkv8 + ((size_t)gcg * PIX + m0 + m) * 8) = vv;
        }
    } else {
        float* outp = (float*)Cout;
        #pragma unroll
        for (int fm = 0; fm < 4; fm++) {
            #pragma unroll
            for (int fn = 0; fn < 2; fn++) {
                int n = n0 + wn * 32 + fn * 16 + lr;
                float bv = bias0[n];
                #pragma unroll
                for (int e = 0; e < 4; e++) {
                    int m = m0 + wm * 64 + fm * 16 + lk * 4 + e;
                    outp[(size_t)m * 192 + n] = acc[fm][fn][e] + bv;
                }
            }
        }
    }
}

// ---------------- fused: depthwise(k,v) + cosine attention + PV -----------------------
// Block = 512 thr = 8 waves per (head, 32x2 pixel tile). Wave w handles 4 channels
// (he*32 + w*4). Lane (0..63) = pixel. Per-head reductions via LDS float atomics.
__global__ __launch_bounds__(512)
void fused6_kernel(const unsigned short* __restrict__ qkv8, const float* __restrict__ deform,
                   const float* __restrict__ scale, const float* __restrict__ rb,
                   unsigned short* __restrict__ attnS)
{
    __shared__ float red[64][21];   // per-pixel: qk[0..8], kn[9..17], qn2[18]

    int id = blockIdx.x;              // 4 b * 6 he * 48 ypairs * 3 strips = 3456
    int strip = id % 3;
    int yp = (id / 3) % 48;
    int he = (id / 144) % 6;
    int b = id / 864;
    int tid = threadIdx.x;
    int l = tid & 63;
    int wsub = tid >> 6;              // 0..7 channel-quad split
    int X = strip * 32 + (l & 31);
    int Y = yp * 2 + (l >> 5);
    int pimg = Y * 96 + X;
    size_t ibase = (size_t)b * IMG;

    for (int i = tid; i < 64 * 21; i += 512) (&red[0][0])[i] = 0.f;
    __syncthreads();

    int c0 = __builtin_amdgcn_readfirstlane(he * 32 + wsub * 4);
    int qg = c0 >> 3;                 // channel-group 0..23
    int hh = (c0 >> 2) & 1;           // which half of the 8-granule
    const unsigned short* qb = qkv8 + ((size_t)qg * PIX + ibase) * 8 + hh * 4;
    const unsigned short* kb = qkv8 + ((size_t)(24 + qg) * PIX + ibase) * 8 + hh * 4;
    const unsigned short* vb = qkv8 + ((size_t)(48 + qg) * PIX + ibase) * 8 + hh * 4;

    int off[9];
    unsigned okm = 0;
    #pragma unroll
    for (int pos = 0; pos < 9; pos++) {
        int dy = pos / 3 - 1, dx = pos % 3 - 1;
        int yy = Y + dy, xx = X + dx;
        bool ok = (yy >= 0) && (yy < 96) && (xx >= 0) && (xx < 96);
        okm |= (ok ? 1u : 0u) << pos;
        off[pos] = ok ? (yy * 96 + xx) : pimg;
    }

    // ---- pass 1 loads: q + 9 k-taps (8B each, coalesced), all issued up front ----
    uint2v qd = *(const uint2v*)(qb + (size_t)pimg * 8);
    uint2v kd[9];
    #pragma unroll
    for (int pos = 0; pos < 9; pos++) kd[pos] = *(const uint2v*)(kb + (size_t)off[pos] * 8);
    #pragma unroll
    for (int pos = 0; pos < 9; pos++)
        if (!((okm >> pos) & 1)) { kd[pos].x = 0; kd[pos].y = 0; }

    float qk[9], kn[9];
    #pragma unroll
    for (int t = 0; t < 9; t++) { qk[t] = 0.f; kn[t] = 0.f; }
    float qn2 = 0.f;

    #pragma unroll
    for (int ci = 0; ci < 4; ci++) {
        int c = c0 + ci;
        unsigned qw = ((const unsigned*)&qd)[ci >> 1];
        float q = (ci & 1) ? bfhi(qw) : bflo(qw);
        qn2 = fmaf(q, q, qn2);
        float kin[9];
        #pragma unroll
        for (int pos = 0; pos < 9; pos++) {
            unsigned dw = ((const unsigned*)&kd[pos])[ci >> 1];
            kin[pos] = (ci & 1) ? bfhi(dw) : bflo(dw);
        }
        float ktap[9];
        #pragma unroll
        for (int t = 0; t < 9; t++) ktap[t] = kin[t];
        #pragma unroll
        for (int pos = 0; pos < 9; pos++) {
            const float* wr = deform + ((size_t)pos * 192 + c) * 9;   // wave-uniform
            #pragma unroll
            for (int t = 0; t < 9; t++) ktap[t] = fmaf(kin[pos], wr[t], ktap[t]);
        }
        #pragma unroll
        for (int t = 0; t < 9; t++) {
            qk[t] = fmaf(q, ktap[t], qk[t]);
            kn[t] = fmaf(ktap[t], ktap[t], kn[t]);
        }
    }

    // ---- issue pass-2 v loads now; latency hides under reduce+softmax ----
    uint2v vd[9];
    #pragma unroll
    for (int pos = 0; pos < 9; pos++) vd[pos] = *(const uint2v*)(vb + (size_t)off[pos] * 8);

    #pragma unroll
    for (int t = 0; t < 9; t++) atomicAdd(&red[l][t], qk[t]);
    #pragma unroll
    for (int t = 0; t < 9; t++) atomicAdd(&red[l][9 + t], kn[t]);
    atomicAdd(&red[l][18], qn2);

    #pragma unroll
    for (int pos = 0; pos < 9; pos++)
        if (!((okm >> pos) & 1)) { vd[pos].x = 0; vd[pos].y = 0; }
    __syncthreads();

    // ---- softmax (redundant per wave, identical inputs) ----
    float qn = rsqrtf(fmaxf(red[l][18], EPS));
    float es = expf(scale[he]);
    float w[9];
    float m = -1e30f;
    #pragma unroll
    for (int t = 0; t < 9; t++) {
        float lg = es * qn * red[l][t] * rsqrtf(fmaxf(red[l][9 + t], EPS));
        lg += (((okm >> t) & 1) ? 0.f : -100.f) + rb[he * 9 + t];
        w[t] = lg;
        m = fmaxf(m, lg);
    }
    float ssum = 0.f;
    #pragma unroll
    for (int t = 0; t < 9; t++) { w[t] = expf(w[t] - m); ssum += w[t]; }
    float inv = 1.f / ssum;
    #pragma unroll
    for (int t = 0; t < 9; t++) w[t] *= inv;

    // ---- pass 2: v depthwise folded through softmax weights ----
    unsigned short o4[4];
    #pragma unroll
    for (int ci = 0; ci < 4; ci++) {
        int c = c0 + ci;
        float vin[9];
        #pragma unroll
        for (int pos = 0; pos < 9; pos++) {
            unsigned dw = ((const unsigned*)&vd[pos])[ci >> 1];
            vin[pos] = (ci & 1) ? bfhi(dw) : bflo(dw);
        }
        float acc = 0.f;
        #pragma unroll
        for (int pos = 0; pos < 9; pos++) {
            const float* wr = deform + ((size_t)pos * 192 + c) * 9;   // wave-uniform
            float sp = w[pos];
            #pragma unroll
            for (int t = 0; t < 9; t++) sp = fmaf(w[t], wr[t], sp);
            acc = fmaf(vin[pos], sp, acc);
        }
        o4[ci] = f2bf(acc);
    }
    short4v ov;
    #pragma unroll
    for (int ci = 0; ci < 4; ci++) ov[ci] = (short)o4[ci];
    *(short4v*)(attnS + (ibase + pimg) * 192 + c0) = ov;
}

extern "C" void kernel_launch(void* const* d_in, const int* in_sizes, int n_in,
                              void* d_out, int out_size, void* d_ws, size_t ws_size,
                              hipStream_t stream) {
    const float* x       = (const float*)d_in[0];
    const float* qkv_w   = (const float*)d_in[1];
    const float* q_bias  = (const float*)d_in[2];
    const float* v_bias  = (const float*)d_in[3];
    const float* deform  = (const float*)d_in[4];
    const float* scale   = (const float*)d_in[5];
    const float* cpb_w1  = (const float*)d_in[6];
    const float* cpb_b1  = (const float*)d_in[7];
    const float* cpb_w2  = (const float*)d_in[8];
    const float* proj_w  = (const float*)d_in[9];
    const float* proj_b  = (const float*)d_in[10];
    float* out = (float*)d_out;

    char* ws = (char*)d_ws;
    float*          rb    = (float*)ws;                               // 256 B
    unsigned short* xs    = (unsigned short*)(ws + 256);              // PIX*192*2 = 14,155,776 B
    unsigned short* Bt    = (unsigned short*)(ws + 256 + 14155776);   // 221,184 B
    unsigned short* Bt2   = (unsigned short*)(ws + 256 + 14155776 + 221184);          // 73,728 B
    unsigned short* qkv8  = (unsigned short*)(ws + 256 + 14155776 + 221184 + 73728);  // 42,467,328 B
    unsigned short* attnS = (unsigned short*)(ws + 256 + 14155776 + 221184 + 73728 + 42467328); // 14,155,776 B

    relbias_kernel<<<1, 512, 0, stream>>>(cpb_w1, cpb_b1, cpb_w2, rb);
    prep_kernel<<<2048, 256, 0, stream>>>(x, qkv_w, proj_w, xs, Bt, Bt2);
    mfma_gemm_kernel<0><<<dim3(576 / 64, PIX / 128), 256, 0, stream>>>(
        xs, Bt, (void*)qkv8, q_bias, v_bias);
    fused6_kernel<<<3456, 512, 0, stream>>>(qkv8, deform, scale, rb, attnS);
    mfma_gemm_kernel<1><<<dim3(192 / 64, PIX / 128), 256, 0, stream>>>(
        attnS, Bt2, (void*)out, proj_b, nullptr);
}

// Round 9
// 269.982 us; speedup vs baseline: 1.3827x; 1.3827x over previous
//
#include <hip/hip_runtime.h>
#include <math.h>

#define EPS 1.55e-05f
#define PIX 36864   // 4*96*96
#define IMG 9216    // 96*96

typedef __attribute__((ext_vector_type(8))) short short8v;
typedef __attribute__((ext_vector_type(4))) float float4v;
typedef __attribute__((ext_vector_type(4))) unsigned short ushort4v;
typedef __attribute__((ext_vector_type(4))) unsigned int uint4v;

static __device__ __forceinline__ unsigned short f2bf(float f) {
    unsigned u = __float_as_uint(f);
    unsigned r = (u + 0x7FFFu + ((u >> 16) & 1u)) >> 16;
    return (unsigned short)r;
}
static __device__ __forceinline__ float bflo(unsigned d) { return __uint_as_float(d << 16); }
static __device__ __forceinline__ float bfhi(unsigned d) { return __uint_as_float(d & 0xffff0000u); }

// ---------------- relative position bias (6 heads x 9 taps) ----------------
__global__ __launch_bounds__(512)
void relbias_kernel(const float* __restrict__ w1, const float* __restrict__ b1,
                    const float* __restrict__ w2, float* __restrict__ rb)
{
    __shared__ float hid[9][512];
    int i = threadIdx.x;
    const float s0 = -0.7739760316291208f, s2 = 0.7739760316291208f;
    float sv[3]; sv[0] = s0; sv[1] = 0.f; sv[2] = s2;
    float w1a = w1[i], w1b = w1[512 + i], bb = b1[i];
    #pragma unroll
    for (int j = 0; j < 9; j++) {
        float t0 = sv[j / 3], t1 = sv[j % 3];
        hid[j][i] = fmaxf(t0 * w1a + t1 * w1b + bb, 0.f);
    }
    __syncthreads();
    if (i < 54) {
        int he = i / 9, t = i % 9, j = 8 - t;
        float acc = 0.f;
        for (int u = 0; u < 512; u++) acc += hid[j][u] * w2[u * 6 + he];
        rb[he * 9 + t] = 16.f / (1.f + expf(-acc));
    }
}

// ---------------- prep: x->bf16, qkv_w^T->bf16, proj_w^T->bf16 ----------------
__global__ __launch_bounds__(256)
void prep_kernel(const float* __restrict__ x, const float* __restrict__ qkv_w,
                 const float* __restrict__ proj_w,
                 unsigned short* __restrict__ xs, unsigned short* __restrict__ Bt,
                 unsigned short* __restrict__ Bt2)
{
    int tid = blockIdx.x * 256 + threadIdx.x;
    int stride = gridDim.x * 256;
    int total_x4 = PIX * 192 / 4;
    for (int i = tid; i < total_x4; i += stride) {
        float4 v = ((const float4*)x)[i];
        ushort4v o;
        o.x = f2bf(v.x); o.y = f2bf(v.y); o.z = f2bf(v.z); o.w = f2bf(v.w);
        ((ushort4v*)xs)[i] = o;
    }
    for (int i = tid; i < 576 * 192; i += stride) {
        int n = i / 192, k = i - n * 192;
        Bt[i] = f2bf(qkv_w[k * 576 + n]);
    }
    for (int i = tid; i < 192 * 192; i += stride) {
        int n = i / 192, k = i - n * 192;
        Bt2[i] = f2bf(proj_w[k * 192 + n]);
    }
}

// ---------------- MFMA bf16 GEMM (unchanged from R6) ----------------
template<int MODE>
__global__ __launch_bounds__(256)
void mfma_gemm_kernel(const unsigned short* __restrict__ Abf,
                      const unsigned short* __restrict__ Btb,
                      void* __restrict__ Cout,
                      const float* __restrict__ bias0,
                      const float* __restrict__ bias1)
{
    const int K = 192;
    __shared__ short smem[128 * 64 + 64 * 64];
    short* As = smem;
    short* Bs = smem + 128 * 64;
    int tid = threadIdx.x;
    int m0 = blockIdx.y * 128;
    int n0 = blockIdx.x * 64;
    int lane = tid & 63, wid = tid >> 6;
    int wm = wid >> 1, wn = wid & 1;
    int lr = lane & 15, lk = lane >> 4;

    float4v acc[4][2];
    #pragma unroll
    for (int a = 0; a < 4; a++)
        #pragma unroll
        for (int b = 0; b < 2; b++)
            #pragma unroll
            for (int e = 0; e < 4; e++) acc[a][b][e] = 0.f;

    int sr = tid >> 3;
    int sc = tid & 7;
    for (int k0 = 0; k0 < K; k0 += 64) {
        #pragma unroll
        for (int i = 0; i < 4; i++) {
            int r = sr + i * 32;
            short8v v = *(const short8v*)(Abf + (size_t)(m0 + r) * K + k0 + sc * 8);
            *(short8v*)(As + r * 64 + ((sc ^ (r & 7)) * 8)) = v;
        }
        #pragma unroll
        for (int i = 0; i < 2; i++) {
            int r = sr + i * 32;
            short8v v = *(const short8v*)(Btb + (size_t)(n0 + r) * K + k0 + sc * 8);
            *(short8v*)(Bs + r * 64 + ((sc ^ (r & 7)) * 8)) = v;
        }
        __syncthreads();
        #pragma unroll
        for (int ks = 0; ks < 2; ks++) {
            short8v af[4], bf[2];
            #pragma unroll
            for (int fm = 0; fm < 4; fm++) {
                int r = wm * 64 + fm * 16 + lr;
                int c = (ks * 4 + lk) ^ (r & 7);
                af[fm] = *(const short8v*)(As + r * 64 + c * 8);
            }
            #pragma unroll
            for (int fn = 0; fn < 2; fn++) {
                int r = wn * 32 + fn * 16 + lr;
                int c = (ks * 4 + lk) ^ (r & 7);
                bf[fn] = *(const short8v*)(Bs + r * 64 + c * 8);
            }
            #pragma unroll
            for (int fm = 0; fm < 4; fm++)
                #pragma unroll
                for (int fn = 0; fn < 2; fn++)
                    acc[fm][fn] = __builtin_amdgcn_mfma_f32_16x16x32_bf16(
                        af[fm], bf[fn], acc[fm][fn], 0, 0, 0);
        }
        __syncthreads();
    }

    if (MODE == 0) {
        const int TP = 74;
        unsigned short* T = (unsigned short*)smem;
        #pragma unroll
        for (int fm = 0; fm < 4; fm++) {
            #pragma unroll
            for (int fn = 0; fn < 2; fn++) {
                int n = wn * 32 + fn * 16 + lr;
                int gn = n0 + n;
                float bv = (gn < 192) ? bias0[gn] : ((gn < 384) ? 0.f : bias1[gn - 384]);
                #pragma unroll
                for (int e = 0; e < 4; e++) {
                    int m = wm * 64 + fm * 16 + lk * 4 + e;
                    T[m * TP + n] = f2bf(acc[fm][fn][e] + bv);
                }
            }
        }
        __syncthreads();
        unsigned short* qkv8 = (unsigned short*)Cout;
        #pragma unroll
        for (int i = 0; i < 4; i++) {
            int u = tid + 256 * i;
            int m = u & 127, cgl = u >> 7;
            short8v vv = *(const short8v*)(T + m * TP + cgl * 8);
            int gcg = (n0 >> 3) + cgl;
            *(short8v*)(qkv8 + ((size_t)gcg * PIX + m0 + m) * 8) = vv;
        }
    } else {
        float* outp = (float*)Cout;
        #pragma unroll
        for (int fm = 0; fm < 4; fm++) {
            #pragma unroll
            for (int fn = 0; fn < 2; fn++) {
                int n = n0 + wn * 32 + fn * 16 + lr;
                float bv = bias0[n];
                #pragma unroll
                for (int e = 0; e < 4; e++) {
                    int m = m0 + wm * 64 + fm * 16 + lk * 4 + e;
                    outp[(size_t)m * 192 + n] = acc[fm][fn][e] + bv;
                }
            }
        }
    }
}

// ---------------- fused: LDS-staged depthwise(k,v) + cosine attention + PV ------------
// Block = 128 thr = 2 waves per (16x4 pixel tile, head). Wave w owns channels
// w*16..w*16+15 (wave-uniform -> deform rows are scalar loads). k/v halo tile (18x6,
// zero-filled) staged in LDS; taps are ds_read_b128. V prefetched to regs during pass1.
__global__ __launch_bounds__(128)
void fused7_kernel(const unsigned short* __restrict__ qkv8, const float* __restrict__ deform,
                   const float* __restrict__ scale, const float* __restrict__ rb,
                   unsigned short* __restrict__ attnS)
{
    __shared__ unsigned short kv[4][108][8];   // [head-local g8][halo px][8ch]
    __shared__ float red[64][21];              // per-pixel qk[0..8], kn[9..17], qn2[18]

    int id = blockIdx.x;                 // 576 tiles * 6 heads
    int he = id % 6;
    int tile = id / 6;
    int b = tile / 144;
    int t2 = tile - b * 144;
    int x0 = (t2 % 6) * 16, y0 = (t2 / 6) * 4;
    int tid = threadIdx.x;
    int l = tid & 63;
    int w = __builtin_amdgcn_readfirstlane(tid >> 6);   // channel-half, wave-uniform
    int lx = l & 15, ly = l >> 4;
    int X = x0 + lx, Y = y0 + ly;
    int pimg = Y * 96 + X;
    size_t ibase = (size_t)b * IMG;

    for (int i = tid; i < 64 * 21; i += 128) (&red[0][0])[i] = 0.f;

    // q: this wave's two 8-ch granules for its pixel
    int g8q = he * 4 + w * 2;
    uint4v qd[2];
    qd[0] = *(const uint4v*)(qkv8 + ((size_t)g8q * PIX + ibase + pimg) * 8);
    qd[1] = *(const uint4v*)(qkv8 + ((size_t)(g8q + 1) * PIX + ibase + pimg) * 8);

    // stage k halo tile (zero-filled), and prefetch v tile into regs
    int kgbase = 24 + he * 4;
    int vgbase = 48 + he * 4;
    #pragma unroll
    for (int r = 0; r < 4; r++) {
        int i = tid + r * 128;
        if (i < 432) {
            int gg = i / 108, hp = i - gg * 108;
            int hy = hp / 18, hx = hp - hy * 18;
            int gx = x0 - 1 + hx, gy = y0 - 1 + hy;
            bool ok = (gx >= 0) && (gx < 96) && (gy >= 0) && (gy < 96);
            uint4v v; v.x = 0; v.y = 0; v.z = 0; v.w = 0;
            if (ok) v = *(const uint4v*)(qkv8 + ((size_t)(kgbase + gg) * PIX + ibase + gy * 96 + gx) * 8);
            *(uint4v*)&kv[gg][hp][0] = v;
        }
    }
    uint4v vst[4];
    #pragma unroll
    for (int r = 0; r < 4; r++) {
        int i = tid + r * 128;
        vst[r].x = 0; vst[r].y = 0; vst[r].z = 0; vst[r].w = 0;
        if (i < 432) {
            int gg = i / 108, hp = i - gg * 108;
            int hy = hp / 18, hx = hp - hy * 18;
            int gx = x0 - 1 + hx, gy = y0 - 1 + hy;
            bool ok = (gx >= 0) && (gx < 96) && (gy >= 0) && (gy < 96);
            if (ok) vst[r] = *(const uint4v*)(qkv8 + ((size_t)(vgbase + gg) * PIX + ibase + gy * 96 + gx) * 8);
        }
    }
    __syncthreads();

    // logit validity mask for this pixel
    unsigned okm = 0;
    #pragma unroll
    for (int pos = 0; pos < 9; pos++) {
        int dy = pos / 3 - 1, dx = pos % 3 - 1;
        bool ok = (Y + dy >= 0) && (Y + dy < 96) && (X + dx >= 0) && (X + dx < 96);
        okm |= (ok ? 1u : 0u) << pos;
    }
    const int hp0 = (ly + 1) * 18 + (lx + 1);
    const int dtap[9] = {-19, -18, -17, -1, 0, 1, 17, 18, 19};

    float qk[9], kn[9];
    #pragma unroll
    for (int t = 0; t < 9; t++) { qk[t] = 0.f; kn[t] = 0.f; }
    float qn2 = 0.f;

    // ---- pass 1: k taps from LDS ----
    #pragma unroll
    for (int g = 0; g < 2; g++) {
        int g8 = w * 2 + g;
        uint4v kd[9];
        #pragma unroll
        for (int pos = 0; pos < 9; pos++)
            kd[pos] = *(const uint4v*)&kv[g8][hp0 + dtap[pos]][0];
        #pragma unroll
        for (int ci = 0; ci < 8; ci++) {
            int c = he * 32 + (w * 2 + g) * 8 + ci;
            unsigned qw = ((const unsigned*)&qd[g])[ci >> 1];
            float q = (ci & 1) ? bfhi(qw) : bflo(qw);
            qn2 = fmaf(q, q, qn2);
            float kin[9];
            #pragma unroll
            for (int pos = 0; pos < 9; pos++) {
                unsigned dw = ((const unsigned*)&kd[pos])[ci >> 1];
                kin[pos] = (ci & 1) ? bfhi(dw) : bflo(dw);
            }
            float ktap[9];
            #pragma unroll
            for (int t = 0; t < 9; t++) ktap[t] = kin[t];
            #pragma unroll
            for (int pos = 0; pos < 9; pos++) {
                const float* wr = deform + ((size_t)pos * 192 + c) * 9;   // scalar loads
                #pragma unroll
                for (int t = 0; t < 9; t++) ktap[t] = fmaf(kin[pos], wr[t], ktap[t]);
            }
            #pragma unroll
            for (int t = 0; t < 9; t++) {
                qk[t] = fmaf(q, ktap[t], qk[t]);
                kn[t] = fmaf(ktap[t], ktap[t], kn[t]);
            }
        }
    }

    // ---- combine the 2 waves' partials ----
    #pragma unroll
    for (int t = 0; t < 9; t++) atomicAdd(&red[l][t], qk[t]);
    #pragma unroll
    for (int t = 0; t < 9; t++) atomicAdd(&red[l][9 + t], kn[t]);
    atomicAdd(&red[l][18], qn2);
    __syncthreads();

    // ---- softmax (redundant per wave) ----
    float qn = rsqrtf(fmaxf(red[l][18], EPS));
    float es = expf(scale[he]);
    float wgt[9];
    float m = -1e30f;
    #pragma unroll
    for (int t = 0; t < 9; t++) {
        float lg = es * qn * red[l][t] * rsqrtf(fmaxf(red[l][9 + t], EPS));
        lg += (((okm >> t) & 1) ? 0.f : -100.f) + rb[he * 9 + t];
        wgt[t] = lg;
        m = fmaxf(m, lg);
    }
    float ssum = 0.f;
    #pragma unroll
    for (int t = 0; t < 9; t++) { wgt[t] = expf(wgt[t] - m); ssum += wgt[t]; }
    float inv = 1.f / ssum;
    #pragma unroll
    for (int t = 0; t < 9; t++) wgt[t] *= inv;

    // ---- overwrite LDS with v tile (prefetched regs) ----
    #pragma unroll
    for (int r = 0; r < 4; r++) {
        int i = tid + r * 128;
        if (i < 432) {
            int gg = i / 108, hp = i - gg * 108;
            *(uint4v*)&kv[gg][hp][0] = vst[r];
        }
    }
    __syncthreads();

    // ---- pass 2: v taps from LDS, folded through softmax weights ----
    unsigned short o16[16];
    #pragma unroll
    for (int g = 0; g < 2; g++) {
        int g8 = w * 2 + g;
        uint4v vd[9];
        #pragma unroll
        for (int pos = 0; pos < 9; pos++)
            vd[pos] = *(const uint4v*)&kv[g8][hp0 + dtap[pos]][0];
        #pragma unroll
        for (int ci = 0; ci < 8; ci++) {
            int c = he * 32 + (w * 2 + g) * 8 + ci;
            float vin[9];
            #pragma unroll
            for (int pos = 0; pos < 9; pos++) {
                unsigned dw = ((const unsigned*)&vd[pos])[ci >> 1];
                vin[pos] = (ci & 1) ? bfhi(dw) : bflo(dw);
            }
            float acc = 0.f;
            #pragma unroll
            for (int pos = 0; pos < 9; pos++) {
                const float* wr = deform + ((size_t)pos * 192 + c) * 9;   // scalar loads
                float sp = wgt[pos];
                #pragma unroll
                for (int t = 0; t < 9; t++) sp = fmaf(wgt[t], wr[t], sp);
                acc = fmaf(vin[pos], sp, acc);
            }
            o16[g * 8 + ci] = f2bf(acc);
        }
    }
    unsigned short* orow = attnS + (ibase + pimg) * 192 + he * 32 + w * 16;
    short8v ov0, ov1;
    #pragma unroll
    for (int ci = 0; ci < 8; ci++) { ov0[ci] = (short)o16[ci]; ov1[ci] = (short)o16[8 + ci]; }
    *(short8v*)(orow) = ov0;
    *(short8v*)(orow + 8) = ov1;
}

extern "C" void kernel_launch(void* const* d_in, const int* in_sizes, int n_in,
                              void* d_out, int out_size, void* d_ws, size_t ws_size,
                              hipStream_t stream) {
    const float* x       = (const float*)d_in[0];
    const float* qkv_w   = (const float*)d_in[1];
    const float* q_bias  = (const float*)d_in[2];
    const float* v_bias  = (const float*)d_in[3];
    const float* deform  = (const float*)d_in[4];
    const float* scale   = (const float*)d_in[5];
    const float* cpb_w1  = (const float*)d_in[6];
    const float* cpb_b1  = (const float*)d_in[7];
    const float* cpb_w2  = (const float*)d_in[8];
    const float* proj_w  = (const float*)d_in[9];
    const float* proj_b  = (const float*)d_in[10];
    float* out = (float*)d_out;

    char* ws = (char*)d_ws;
    float*          rb    = (float*)ws;                               // 256 B
    unsigned short* xs    = (unsigned short*)(ws + 256);              // 14,155,776 B
    unsigned short* Bt    = (unsigned short*)(ws + 256 + 14155776);   // 221,184 B
    unsigned short* Bt2   = (unsigned short*)(ws + 256 + 14155776 + 221184);          // 73,728 B
    unsigned short* qkv8  = (unsigned short*)(ws + 256 + 14155776 + 221184 + 73728);  // 42,467,328 B
    unsigned short* attnS = (unsigned short*)(ws + 256 + 14155776 + 221184 + 73728 + 42467328); // 14,155,776 B

    relbias_kernel<<<1, 512, 0, stream>>>(cpb_w1, cpb_b1, cpb_w2, rb);
    prep_kernel<<<2048, 256, 0, stream>>>(x, qkv_w, proj_w, xs, Bt, Bt2);
    mfma_gemm_kernel<0><<<dim3(576 / 64, PIX / 128), 256, 0, stream>>>(
        xs, Bt, (void*)qkv8, q_bias, v_bias);
    fused7_kernel<<<3456, 128, 0, stream>>>(qkv8, deform, scale, rb, attnS);
    mfma_gemm_kernel<1><<<dim3(192 / 64, PIX / 128), 256, 0, stream>>>(
        attnS, Bt2, (void*)out, proj_b, nullptr);
}